// Round 1
// baseline (713.747 us; speedup 1.0000x reference)
//
#include <hip/hip_runtime.h>

typedef unsigned int uint32;
typedef unsigned short ushort16;
typedef __attribute__((ext_vector_type(8))) short bf16x8;
typedef __attribute__((ext_vector_type(4))) float f32x4;

// ---------------------------------------------------------------------------
// Sizes: B=2, L=256, E=512, H=8, D=64.  SCALE = 0.125
// ---------------------------------------------------------------------------

// ===========================================================================
// Wr f32 -> bf16 (RNE). 1024x512 = 524288 elems, 4 per thread.
// ===========================================================================
__device__ __forceinline__ uint32 bf_rne(uint32 u) {
  return (u + 0x7fffu + ((u >> 16) & 1u)) >> 16;
}

__global__ void cvt_wr_kernel(const float* __restrict__ Wr, ushort16* __restrict__ WrBf) {
  int idx = blockIdx.x * 256 + threadIdx.x;   // [0, 131072)
  const uint4* src = (const uint4*)Wr;
  uint4 x = src[idx];
  uint2 o;
  o.x = bf_rne(x.x) | (bf_rne(x.y) << 16);
  o.y = bf_rne(x.z) | (bf_rne(x.w) << 16);
  ((uint2*)WrBf)[idx] = o;
}

// ===========================================================================
// Projection GEMM: Y[m,n] = (sum_k X[m,k] * W[n,k] + bias[n]) * scale
// M=N=K=512.  BM=BN=64, BK=16, 256 threads, 4x4 per thread.
// grid.z selects (X,W,bias,Y,scale) triple (q/k/v); also reused for Wo.
// ===========================================================================
__global__ __launch_bounds__(256) void proj_kernel(
    const float* __restrict__ X0, const float* __restrict__ W0, const float* __restrict__ b0, float* __restrict__ Y0,
    const float* __restrict__ X1, const float* __restrict__ W1, const float* __restrict__ b1, float* __restrict__ Y1,
    const float* __restrict__ X2, const float* __restrict__ W2, const float* __restrict__ b2, float* __restrict__ Y2,
    float scale0) {
  int z = blockIdx.z;
  const float* X = (z == 0) ? X0 : (z == 1) ? X1 : X2;
  const float* W = (z == 0) ? W0 : (z == 1) ? W1 : W2;
  const float* bias = (z == 0) ? b0 : (z == 1) ? b1 : b2;
  float* Y = (z == 0) ? Y0 : (z == 1) ? Y1 : Y2;
  float scale = (z == 0) ? scale0 : 1.0f;

  __shared__ float Xs[16][68];
  __shared__ float Ws[16][68];

  int tid = threadIdx.x;
  int tx = tid & 15, ty = tid >> 4;
  int m0 = blockIdx.x * 64, n0 = blockIdx.y * 64;

  float acc[4][4] = {};

  for (int k0 = 0; k0 < 512; k0 += 16) {
#pragma unroll
    for (int u = 0; u < 4; ++u) {
      int idx = tid + u * 256;           // [0,1024)
      int ml = idx >> 4, kl = idx & 15;
      Xs[kl][ml] = X[(size_t)(m0 + ml) * 512 + k0 + kl];
      Ws[kl][ml] = W[(size_t)(n0 + ml) * 512 + k0 + kl];
    }
    __syncthreads();
#pragma unroll
    for (int kk = 0; kk < 16; ++kk) {
      float4 a = *(const float4*)&Xs[kk][ty * 4];
      float4 w = *(const float4*)&Ws[kk][tx * 4];
      float av[4] = {a.x, a.y, a.z, a.w};
      float wv[4] = {w.x, w.y, w.z, w.w};
#pragma unroll
      for (int i = 0; i < 4; ++i)
#pragma unroll
        for (int jj = 0; jj < 4; ++jj)
          acc[i][jj] += av[i] * wv[jj];
    }
    __syncthreads();
  }
#pragma unroll
  for (int i = 0; i < 4; ++i) {
    int m = m0 + ty * 4 + i;
#pragma unroll
    for (int jj = 0; jj < 4; ++jj) {
      int n = n0 + tx * 4 + jj;
      Y[(size_t)m * 512 + n] = (acc[i][jj] + bias[n]) * scale;
    }
  }
}

// ===========================================================================
// Fused relation-GEMM + score kernel.
// Tile: 64 M-rows (i) x 256 N-cols (2 heads x 128 interleaved rq/rk), K=512.
// m-row = (b, j, i) = relation layout.  8192 blocks, 256 threads (4 waves).
// Wave wv covers cols [wv*64, wv*64+64): head = h0 + (wv>>1), d-base (wv&1)*32.
// Column group g = nn>>4 within head: even g -> rq, odd g -> rk,
// d = (g>>1)*16 + (nn&15)  => frag pairs (fc, fc+1) hold matching d per lane.
// Epilogue: score = sum_d (q+Prq)(k+Prk), 16-lane shuffle reduce, cross-wave
// combine through LDS, scatter to attn[b][i][j][h] (raw scores).
// ===========================================================================
__global__ __launch_bounds__(256, 3) void rel_score_kernel(
    const float* __restrict__ rel,      // [B][j:256][i:256][512]
    const ushort16* __restrict__ wrbf,  // [1024][512] bf16
    const float* __restrict__ qws,      // [B*256][512] (pre-scaled)
    const float* __restrict__ kws,      // [B*256][512]
    float* __restrict__ attn)           // [B][i][j][H] raw scores
{
  __shared__ ushort16 As[64 * 64];     // [m][k] bf16
  __shared__ ushort16 Bs[256 * 64];    // [n_local][k] bf16
  __shared__ float scores[4][64];

  const int tid = threadIdx.x;
  const int lane = tid & 63;
  const int wv = tid >> 6;
  const int blk = blockIdx.x;
  const int hp = blk & 3;
  const int mt = blk >> 2;
  const int b = mt >> 10;
  const int j = (mt >> 2) & 255;
  const int i0 = (mt & 3) << 6;
  const int h0 = hp << 1;

  const float* Abase = rel + (size_t)mt * (64 * 512);

  // B staging: per wave 8 issues of global_load_lds(16B):
  // issue v covers B-rows [wv*64+v*8, +8): lane l -> row +(l>>3), byte (l&7)*16
  int gOff[8];
#pragma unroll
  for (int v = 0; v < 8; ++v) {
    int r_local = wv * 64 + v * 8 + (lane >> 3);
    int hl = r_local >> 7;
    int nn = r_local & 127;
    int g = nn >> 4, t = nn & 15;
    int wr_row = (g & 1) * 512 + (h0 + hl) * 64 + (g >> 1) * 16 + t;
    gOff[v] = wr_row * 512 + (lane & 7) * 8;
  }

  const int arow0 = tid >> 3;        // A staging: row for idx8 = tid
  const int ak8 = (tid & 7) * 8;     // k-chunk (8 floats)

  f32x4 acc[4][4];
#pragma unroll
  for (int a = 0; a < 4; ++a)
#pragma unroll
    for (int c = 0; c < 4; ++c)
      acc[a][c] = (f32x4){0.f, 0.f, 0.f, 0.f};

  const int t15 = lane & 15;
  const int kq = (lane >> 4) * 8;

  for (int k0 = 0; k0 < 512; k0 += 64) {
    // ---- stage A: f32 -> bf16 (truncate) ----
#pragma unroll
    for (int u = 0; u < 2; ++u) {
      int row = arow0 + u * 32;
      const uint4* src = (const uint4*)(Abase + (size_t)row * 512 + k0 + ak8);
      uint4 x = src[0];
      uint4 y = src[1];
      uint4 o;
      o.x = (x.y & 0xffff0000u) | (x.x >> 16);
      o.y = (x.w & 0xffff0000u) | (x.z >> 16);
      o.z = (y.y & 0xffff0000u) | (y.x >> 16);
      o.w = (y.w & 0xffff0000u) | (y.z >> 16);
      *(uint4*)&As[row * 64 + ak8] = o;
    }
    // ---- stage B: async global -> LDS (bf16 Wr, L2-hot) ----
#pragma unroll
    for (int v = 0; v < 8; ++v) {
      __builtin_amdgcn_global_load_lds(
          (const __attribute__((address_space(1))) void*)(wrbf + gOff[v] + k0),
          (__attribute__((address_space(3))) void*)&Bs[wv * 4096 + v * 512],
          16, 0, 0);
    }
    __syncthreads();
    // ---- MFMA ----
#pragma unroll
    for (int kh = 0; kh < 2; ++kh) {
      int kk = kh * 32 + kq;
      bf16x8 af[4], bfr[4];
#pragma unroll
      for (int fr = 0; fr < 4; ++fr)
        af[fr] = *(const bf16x8*)&As[(fr * 16 + t15) * 64 + kk];
#pragma unroll
      for (int fc = 0; fc < 4; ++fc)
        bfr[fc] = *(const bf16x8*)&Bs[(wv * 64 + fc * 16 + t15) * 64 + kk];
#pragma unroll
      for (int fr = 0; fr < 4; ++fr)
#pragma unroll
        for (int fc = 0; fc < 4; ++fc)
          acc[fr][fc] = __builtin_amdgcn_mfma_f32_16x16x32_bf16(
              af[fr], bfr[fc], acc[fr][fc], 0, 0, 0);
    }
    __syncthreads();
  }

  // ---- epilogue: score = sum_d (q + Prq)(k + Prk) ----
  const int hthis = h0 + (wv >> 1);
  const int dbase = (wv & 1) * 32;
  const float* qbase = qws + ((size_t)(b * 256 + i0)) * 512 + hthis * 64;
  const float* krow = kws + ((size_t)(b * 256 + j)) * 512 + hthis * 64;
  const int rgrp = lane >> 4;
#pragma unroll
  for (int fr = 0; fr < 4; ++fr) {
#pragma unroll
    for (int r = 0; r < 4; ++r) {
      int m = fr * 16 + rgrp * 4 + r;
      float s = 0.f;
#pragma unroll
      for (int p = 0; p < 2; ++p) {
        int d = dbase + p * 16 + t15;
        float qv = qbase[(size_t)m * 512 + d];
        float kv = krow[d];
        s += (qv + acc[fr][p * 2][r]) * (kv + acc[fr][p * 2 + 1][r]);
      }
      s += __shfl_xor(s, 1);
      s += __shfl_xor(s, 2);
      s += __shfl_xor(s, 4);
      s += __shfl_xor(s, 8);
      if (t15 == 0) scores[wv][m] = s;
    }
  }
  __syncthreads();
  if (tid < 128) {
    int hl = tid >> 6, m = tid & 63;
    float sc = scores[hl * 2][m] + scores[hl * 2 + 1][m];
    attn[(((size_t)(b * 256 + i0 + m)) * 256 + j) * 8 + (h0 + hl)] = sc;
  }
}

// ===========================================================================
// Masked softmax over j, in place on attn[b][i][j][h].  Block = (b,i).
// ===========================================================================
__global__ __launch_bounds__(256) void softmax_kernel(float* __restrict__ attn,
                                                      const int* __restrict__ adj) {
  __shared__ float sl[2048];
  __shared__ int msk[256];
  int bi = blockIdx.x;                         // b*256 + i
  float* base = attn + (size_t)bi * 2048;
  const int* abase = adj + (size_t)bi * 256;
  int tid = threadIdx.x;
#pragma unroll
  for (int u = 0; u < 8; ++u) sl[tid + u * 256] = base[tid + u * 256];
  msk[tid] = abase[tid];
  __syncthreads();
  int h = tid >> 5, l5 = tid & 31;
  float mx = -INFINITY;
#pragma unroll
  for (int u = 0; u < 8; ++u) {
    int jj = l5 + u * 32;
    if (msk[jj] != 1) mx = fmaxf(mx, sl[jj * 8 + h]);
  }
#pragma unroll
  for (int off = 16; off >= 1; off >>= 1) mx = fmaxf(mx, __shfl_xor(mx, off));
  float ev[8];
  float sum = 0.f;
#pragma unroll
  for (int u = 0; u < 8; ++u) {
    int jj = l5 + u * 32;
    float e = (msk[jj] != 1) ? __expf(sl[jj * 8 + h] - mx) : 0.f;
    ev[u] = e;
    sum += e;
  }
#pragma unroll
  for (int off = 16; off >= 1; off >>= 1) sum += __shfl_xor(sum, off);
  float inv = (sum > 0.f) ? (1.f / sum) : 0.f;
#pragma unroll
  for (int u = 0; u < 8; ++u) {
    int jj = l5 + u * 32;
    sl[jj * 8 + h] = ev[u] * inv;
  }
  __syncthreads();
#pragma unroll
  for (int u = 0; u < 8; ++u) base[tid + u * 256] = sl[tid + u * 256];
}

// ===========================================================================
// o1[b,i,e] = sum_j attn[b,i,j,h(e)] * v[b,j,e].  Block = (b,i), 2 e/thread.
// ===========================================================================
__global__ __launch_bounds__(256) void av_kernel(const float* __restrict__ attn,
                                                 const float* __restrict__ vws,
                                                 float* __restrict__ o1) {
  int bi = blockIdx.x;
  int b = bi >> 8;
  int tid = threadIdx.x;
  const float* wbase = attn + (size_t)bi * 2048;
  const float* vbase = vws + (size_t)b * (256 * 512);
  int e0 = tid, e1 = tid + 256;
  int h0 = e0 >> 6, h1 = e1 >> 6;
  float a0 = 0.f, a1 = 0.f;
  for (int jj = 0; jj < 256; ++jj) {
    float w0 = wbase[jj * 8 + h0];
    float w1 = wbase[jj * 8 + h1];
    const float* vr = vbase + (size_t)jj * 512;
    a0 += w0 * vr[e0];
    a1 += w1 * vr[e1];
  }
  float* orow = o1 + (size_t)bi * 512;
  orow[e0] = a0;
  orow[e1] = a1;
}

// ===========================================================================
// Launch
// ===========================================================================
extern "C" void kernel_launch(void* const* d_in, const int* in_sizes, int n_in,
                              void* d_out, int out_size, void* d_ws, size_t ws_size,
                              hipStream_t stream) {
  const float* queries = (const float*)d_in[0];
  const float* keys    = (const float*)d_in[1];
  const float* values  = (const float*)d_in[2];
  const float* relation = (const float*)d_in[3];
  const int*   adj     = (const int*)d_in[4];
  const float* Wq = (const float*)d_in[5];
  const float* bq = (const float*)d_in[6];
  const float* Wk = (const float*)d_in[7];
  const float* bk = (const float*)d_in[8];
  const float* Wv = (const float*)d_in[9];
  const float* bv = (const float*)d_in[10];
  const float* Wr = (const float*)d_in[11];
  const float* Wo = (const float*)d_in[12];
  const float* bo = (const float*)d_in[13];

  float* out  = (float*)d_out;            // [2*256][512]
  float* attn = out + 262144;             // [2][256][256][8]

  float* ws  = (float*)d_ws;
  float* qws = ws;                        // 262144
  float* kws = ws + 262144;
  float* vws = ws + 524288;
  float* o1  = ws + 786432;
  ushort16* wrbf = (ushort16*)(ws + 1048576);  // 524288 bf16

  cvt_wr_kernel<<<dim3(512), dim3(256), 0, stream>>>(Wr, wrbf);

  proj_kernel<<<dim3(8, 8, 3), dim3(256), 0, stream>>>(
      queries, Wq, bq, qws,
      keys,    Wk, bk, kws,
      values,  Wv, bv, vws,
      0.125f);

  rel_score_kernel<<<dim3(8192), dim3(256), 0, stream>>>(relation, wrbf, qws, kws, attn);

  softmax_kernel<<<dim3(512), dim3(256), 0, stream>>>(attn, adj);

  av_kernel<<<dim3(512), dim3(256), 0, stream>>>(attn, vws, o1);

  proj_kernel<<<dim3(8, 8, 1), dim3(256), 0, stream>>>(
      o1, Wo, bo, out,
      nullptr, nullptr, nullptr, nullptr,
      nullptr, nullptr, nullptr, nullptr,
      1.0f);
}